// Round 13
// baseline (290.274 us; speedup 1.0000x reference)
//
#include <hip/hip_runtime.h>
#include <math.h>

#define N_NODES 100000
#define N_EDGES 1600000
#define F_IN    128
#define F_HID   64
#define F_OUT   40

#define BIN_SHIFT 8
#define NBINS     392          // ceil(100000 / 256)
#define BIN_CAP   5120         // mean ~4082 -> generous headroom
#define FILL_BLOCKS 512

typedef unsigned int  uint;
typedef unsigned short ushort;
typedef __attribute__((ext_vector_type(8))) short bf16x8;   // 4 VGPRs
typedef __attribute__((ext_vector_type(4))) float f32x4;    // MFMA acc

__device__ __forceinline__ unsigned short f2bf(float f) {      // RNE, finite inputs
    uint u = __float_as_uint(f);
    u = (u + 0x7FFF + ((u >> 16) & 1)) >> 16;
    return (unsigned short)u;
}
__device__ __forceinline__ uint pack2bf(float a, float b) {
    return (uint)f2bf(a) | ((uint)f2bf(b) << 16);
}
__device__ __forceinline__ float bf_lo(uint u) { return __uint_as_float(u << 16); }
__device__ __forceinline__ float bf_hi(uint u) { return __uint_as_float(u & 0xFFFF0000u); }

// ---------------- prep: bin cursor init + W1 transpose to bf16 Wt[n(64)][k(128)] --
__global__ void prep_kernel(const float* __restrict__ W, uint* __restrict__ Wt,
                            int* __restrict__ bcursor) {
    int tid = threadIdx.x;                        // 512 threads
    if (tid < NBINS) bcursor[tid] = tid * BIN_CAP;
    for (int i = tid; i < 4096; i += 512) {       // uint index: c*64 + kpair
        int c  = i >> 6;
        int kp = i & 63;
        Wt[i] = pack2bf(W[(2 * kp) * F_HID + c], W[(2 * kp + 1) * F_HID + c]);
    }
}

// ---------------- binned scatter of packed (src | ldst<<17) into padded bins ------
__global__ void binfill_kernel(const int* __restrict__ src, const int* __restrict__ dst,
                               int* __restrict__ bcursor, int* __restrict__ bins, int E) {
    __shared__ int lcount[NBINS];
    __shared__ int gbase[NBINS];
    int tid = threadIdx.x;
    for (int i = tid; i < NBINS; i += 256) lcount[i] = 0;
    __syncthreads();
    int chunk = (E + gridDim.x - 1) / gridDim.x;
    int beg = blockIdx.x * chunk, end = min(E, beg + chunk);
    for (int e = beg + tid; e < end; e += 256)
        atomicAdd(&lcount[dst[e] >> BIN_SHIFT], 1);
    __syncthreads();
    for (int i = tid; i < NBINS; i += 256) {
        gbase[i] = lcount[i] ? atomicAdd(&bcursor[i], lcount[i]) : 0;
        lcount[i] = 0;
    }
    __syncthreads();
    for (int e = beg + tid; e < end; e += 256) {
        int d = dst[e];
        int b = d >> BIN_SHIFT;
        int p = atomicAdd(&lcount[b], 1);
        bins[gbase[b] + p] = src[e] | ((d & 255) << 17);
    }
}

// ---------------- per-bin counting sort; emits rowstart/rowcnt/dinv/csr -----------
__global__ void binsort_kernel(const int* __restrict__ bcursor, const int* __restrict__ bins,
                               int* __restrict__ csr, int* __restrict__ rowstart,
                               int* __restrict__ rowcnt, float* __restrict__ dinv) {
    __shared__ int hist[256];
    __shared__ int scan[256];
    __shared__ int cur[256];
    __shared__ int sorted[BIN_CAP];
    int b = blockIdx.x, t = threadIdx.x;          // 512 threads
    int base = b * BIN_CAP;
    int cnt = bcursor[b] - base;
    if (t < 256) hist[t] = 0;
    __syncthreads();
    for (int i = t; i < cnt; i += 512)
        atomicAdd(&hist[(unsigned)bins[base + i] >> 17], 1);
    __syncthreads();
    int v = 0;
    if (t < 256) { v = hist[t]; scan[t] = v; }
    __syncthreads();
    for (int off = 1; off < 256; off <<= 1) {
        int u = (t < 256 && t >= off) ? scan[t - off] : 0;
        __syncthreads();
        if (t < 256) scan[t] += u;
        __syncthreads();
    }
    if (t < 256) {
        int excl = scan[t] - v;
        cur[t] = excl;
        int node = (b << BIN_SHIFT) + t;
        if (node < N_NODES) {
            rowstart[node] = base + excl;
            rowcnt[node]   = v;
            dinv[node] = rsqrtf((float)v + 1.0f);   // +1 self-loop
        }
    }
    __syncthreads();
    for (int i = t; i < cnt; i += 512) {
        int p   = bins[base + i];
        int pos = atomicAdd(&cur[(unsigned)p >> 17], 1);
        sorted[pos] = p & 0x1FFFF;
    }
    __syncthreads();
    for (int i = t; i < cnt; i += 512)
        csr[base + i] = sorted[i];
}

// ---------------- GEMM1 (MFMA): h1b[N,64](bf16) = bf16(x) @ bf16(W1) ----------------
#define XPITCH 68   // uints per row (64 + 4 pad)
__global__ __launch_bounds__(256) void gemm1_kernel(const float* __restrict__ x,
                                                    const uint* __restrict__ Wt,
                                                    ushort* __restrict__ h, int n) {
    __shared__ __align__(16) uint Xu[64 * XPITCH];
    __shared__ __align__(16) uint Wu[64 * XPITCH];
    int tid = threadIdx.x;
    int node0 = blockIdx.x * 64;

    {
        int c = tid >> 2, qq = tid & 3;
        const uint4* gsrc = (const uint4*)&Wt[c * 64 + qq * 16];
        uint4* ldst = (uint4*)&Wu[c * XPITCH + qq * 16];
        #pragma unroll
        for (int j = 0; j < 4; ++j) ldst[j] = gsrc[j];
    }
    {
        int row = tid >> 2, qq = tid & 3;
        int node = node0 + row;
        uint4* ldst = (uint4*)&Xu[row * XPITCH + qq * 16];
        if (node < n) {
            const float4* gsrc = (const float4*)&x[(size_t)node * F_IN + qq * 32];
            #pragma unroll
            for (int j = 0; j < 4; ++j) {
                float4 a = gsrc[2 * j], b = gsrc[2 * j + 1];
                uint4 o;
                o.x = pack2bf(a.x, a.y); o.y = pack2bf(a.z, a.w);
                o.z = pack2bf(b.x, b.y); o.w = pack2bf(b.z, b.w);
                ldst[j] = o;
            }
        } else {
            uint4 z = make_uint4(0, 0, 0, 0);
            #pragma unroll
            for (int j = 0; j < 4; ++j) ldst[j] = z;
        }
    }
    __syncthreads();

    int wv   = tid >> 6;
    int lane = tid & 63;
    int lrow = lane & 15;
    int quad = lane >> 4;

    bf16x8 bfrag[4][4];
    #pragma unroll
    for (int t = 0; t < 4; ++t)
        #pragma unroll
        for (int s = 0; s < 4; ++s)
            bfrag[t][s] = *(const bf16x8*)&Wu[(t * 16 + lrow) * XPITCH + s * 16 + quad * 4];

    f32x4 acc[4];
    #pragma unroll
    for (int t = 0; t < 4; ++t) acc[t] = (f32x4){0.f, 0.f, 0.f, 0.f};

    #pragma unroll
    for (int s = 0; s < 4; ++s) {
        bf16x8 afrag = *(const bf16x8*)&Xu[(wv * 16 + lrow) * XPITCH + s * 16 + quad * 4];
        #pragma unroll
        for (int t = 0; t < 4; ++t)
            acc[t] = __builtin_amdgcn_mfma_f32_16x16x32_bf16(afrag, bfrag[t][s], acc[t], 0, 0, 0);
    }

    #pragma unroll
    for (int t = 0; t < 4; ++t) {
        #pragma unroll
        for (int i = 0; i < 4; ++i) {
            int node = node0 + wv * 16 + quad * 4 + i;
            if (node < n) h[(size_t)node * F_HID + t * 16 + lrow] = f2bf(acc[t][i]);
        }
    }
}

// ---------------- layer-1 gather + combine + ReLU + fused GEMM2 -------------------
// 1 node/wave; gather as before; epilogue computes h2[node][40] = relu_out1 @ W2.
#define W2P 41   // LDS pitch for W2 (2-way bank aliasing max, free)
__global__ void agg1_kernel(const int* __restrict__ rowstart, const int* __restrict__ rowcnt,
                            const int* __restrict__ csr, const float* __restrict__ dinv,
                            const ushort* __restrict__ h, const float* __restrict__ b,
                            const float* __restrict__ W2, ushort* __restrict__ h2,
                            int n) {
    __shared__ float W2l[F_HID * W2P];   // 10.5 KB
    int tid = threadIdx.x;
    for (int i = tid; i < F_HID * F_OUT; i += 256) {
        int k = i / F_OUT, j = i - k * F_OUT;
        W2l[k * W2P + j] = W2[i];
    }
    __syncthreads();

    int node = blockIdx.x * 4 + (tid >> 6);      // grid is exactly N/4 -> node < n
    int lane = tid & 63;
    int slot = lane >> 3;        // 0..7
    int c    = lane & 7;         // chunk -> features c*8 .. c*8+7
    int beg = rowstart[node], end = beg + rowcnt[node];
    float acc[8] = {0.f,0.f,0.f,0.f,0.f,0.f,0.f,0.f};
    for (int base = beg; base < end; base += 64) {
        int idx = base + lane;
        int   sid = 0; float wgt = 0.f;
        if (idx < end) { sid = csr[idx]; wgt = dinv[sid]; }
        int cnt    = min(64, end - base);
        int groups = (cnt + 7) >> 3;
        int g = 0;
        for (; g + 2 <= groups; g += 2) {
            int   sA = __shfl(sid, g * 8 + slot);
            float wA = __shfl(wgt, g * 8 + slot);
            int   sB = __shfl(sid, g * 8 + 8 + slot);
            float wB = __shfl(wgt, g * 8 + 8 + slot);
            uint4 hA = *(const uint4*)&h[(size_t)sA * F_HID + (c << 3)];
            uint4 hB = *(const uint4*)&h[(size_t)sB * F_HID + (c << 3)];
            acc[0] += bf_lo(hA.x) * wA; acc[1] += bf_hi(hA.x) * wA;
            acc[2] += bf_lo(hA.y) * wA; acc[3] += bf_hi(hA.y) * wA;
            acc[4] += bf_lo(hA.z) * wA; acc[5] += bf_hi(hA.z) * wA;
            acc[6] += bf_lo(hA.w) * wA; acc[7] += bf_hi(hA.w) * wA;
            acc[0] += bf_lo(hB.x) * wB; acc[1] += bf_hi(hB.x) * wB;
            acc[2] += bf_lo(hB.y) * wB; acc[3] += bf_hi(hB.y) * wB;
            acc[4] += bf_lo(hB.z) * wB; acc[5] += bf_hi(hB.z) * wB;
            acc[6] += bf_lo(hB.w) * wB; acc[7] += bf_hi(hB.w) * wB;
        }
        if (g < groups) {
            int   sA = __shfl(sid, g * 8 + slot);
            float wA = __shfl(wgt, g * 8 + slot);
            uint4 hA = *(const uint4*)&h[(size_t)sA * F_HID + (c << 3)];
            acc[0] += bf_lo(hA.x) * wA; acc[1] += bf_hi(hA.x) * wA;
            acc[2] += bf_lo(hA.y) * wA; acc[3] += bf_hi(hA.y) * wA;
            acc[4] += bf_lo(hA.z) * wA; acc[5] += bf_hi(hA.z) * wA;
            acc[6] += bf_lo(hA.w) * wA; acc[7] += bf_hi(hA.w) * wA;
        }
    }
    // butterfly: after this EVERY lane holds the full sums for its chunk c
    #pragma unroll
    for (int m = 8; m < 64; m <<= 1) {
        #pragma unroll
        for (int k = 0; k < 8; ++k) acc[k] += __shfl_xor(acc[k], m);
    }
    // out1 row (fp32, all lanes): v[i] = relu(acc*di + self*di^2 + b1)
    float di = dinv[node];
    uint4 hs = *(const uint4*)&h[(size_t)node * F_HID + (c << 3)];
    float self[8] = { bf_lo(hs.x), bf_hi(hs.x), bf_lo(hs.y), bf_hi(hs.y),
                      bf_lo(hs.z), bf_hi(hs.z), bf_lo(hs.w), bf_hi(hs.w) };
    float4 b0 = *(const float4*)&b[c << 3];
    float4 b1v = *(const float4*)&b[(c << 3) + 4];
    float bb[8] = { b0.x, b0.y, b0.z, b0.w, b1v.x, b1v.y, b1v.z, b1v.w };
    float v[8];
    #pragma unroll
    for (int k = 0; k < 8; ++k)
        v[k] = fmaxf(acc[k] * di + self[k] * di * di + bb[k], 0.f);

    // fused GEMM2: h2[j] = sum_k v_row[k] * W2[k][j]; round r -> j = r*8 + slot
    float myh2 = 0.f;
    #pragma unroll
    for (int r = 0; r < 5; ++r) {
        int j = r * 8 + slot;
        float p = 0.f;
        #pragma unroll
        for (int i = 0; i < 8; ++i)
            p += v[i] * W2l[(c * 8 + i) * W2P + j];
        p += __shfl_xor(p, 1);
        p += __shfl_xor(p, 2);
        p += __shfl_xor(p, 4);          // all lanes of slot now hold h2[j]
        if (c == r) myh2 = p;
    }
    if (c < 5) h2[(size_t)node * F_OUT + c * 8 + slot] = f2bf(myh2);
}

// ---------------- layer-2 gather + combine + log_softmax (1 node/wave, uint2) -----
__global__ void agg2_kernel(const int* __restrict__ rowstart, const int* __restrict__ rowcnt,
                            const int* __restrict__ csr, const float* __restrict__ dinv,
                            const ushort* __restrict__ h, const float* __restrict__ b,
                            float* __restrict__ out, int n) {
    int node = blockIdx.x * 4 + (threadIdx.x >> 6);
    int lane = threadIdx.x & 63;
    if (node >= n) return;
    int slot = lane / 10;            // 0..6 (lanes 60..63 idle slot)
    int c    = lane - slot * 10;     // chunk -> features c*4..c*4+3
    int beg = rowstart[node], end = beg + rowcnt[node];
    float acc[4] = {0.f, 0.f, 0.f, 0.f};
    for (int base = beg; base < end; base += 60) {
        int idx = base + lane;
        int   sid = 0; float wgt = 0.f;
        if (lane < 60 && idx < end) { sid = csr[idx]; wgt = dinv[sid]; }
        int cnt    = min(60, end - base);
        int groups = (cnt + 5) / 6;
        int g = 0;
        for (; g + 2 <= groups; g += 2) {
            int   slA = (slot < 6) ? (g * 6 + slot) : 60;
            int   slB = (slot < 6) ? (g * 6 + 6 + slot) : 60;
            int   sA = __shfl(sid, slA);
            float wA = __shfl(wgt, slA);
            int   sB = __shfl(sid, slB);
            float wB = __shfl(wgt, slB);
            uint2 hA = *(const uint2*)&h[(size_t)sA * F_OUT + (c << 2)];
            uint2 hB = *(const uint2*)&h[(size_t)sB * F_OUT + (c << 2)];
            acc[0] += bf_lo(hA.x) * wA; acc[1] += bf_hi(hA.x) * wA;
            acc[2] += bf_lo(hA.y) * wA; acc[3] += bf_hi(hA.y) * wA;
            acc[0] += bf_lo(hB.x) * wB; acc[1] += bf_hi(hB.x) * wB;
            acc[2] += bf_lo(hB.y) * wB; acc[3] += bf_hi(hB.y) * wB;
        }
        if (g < groups) {
            int   slA = (slot < 6) ? (g * 6 + slot) : 60;
            int   sA = __shfl(sid, slA);
            float wA = __shfl(wgt, slA);
            uint2 hA = *(const uint2*)&h[(size_t)sA * F_OUT + (c << 2)];
            acc[0] += bf_lo(hA.x) * wA; acc[1] += bf_hi(hA.x) * wA;
            acc[2] += bf_lo(hA.y) * wA; acc[3] += bf_hi(hA.y) * wA;
        }
    }
    // slot reduction: 6 -> 3 -> 1 (3 serial shfl steps)
    float r[4];
    #pragma unroll
    for (int k = 0; k < 4; ++k) {
        float t3 = __shfl(acc[k], lane + 30);          // slots 3..5 -> 0..2
        float s0 = acc[k] + t3;                        // valid for lanes < 30
        float t1 = __shfl(s0, lane + 10);              // slot 1 -> 0
        float t2 = __shfl(s0, lane + 20);              // slot 2 -> 0
        r[k] = s0 + t1 + t2;                           // valid for lanes < 10
    }
    float val[4] = {0.f, 0.f, 0.f, 0.f};
    float m = -INFINITY;
    if (lane < 10) {
        float di = dinv[node];
        uint2 hs = *(const uint2*)&h[(size_t)node * F_OUT + (c << 2)];
        float self[4] = { bf_lo(hs.x), bf_hi(hs.x), bf_lo(hs.y), bf_hi(hs.y) };
        float4 bb = *(const float4*)&b[c << 2];
        float bbv[4] = { bb.x, bb.y, bb.z, bb.w };
        #pragma unroll
        for (int k = 0; k < 4; ++k) {
            val[k] = r[k] * di + self[k] * di * di + bbv[k];
            m = fmaxf(m, val[k]);
        }
    }
    #pragma unroll
    for (int off = 1; off < 16; off <<= 1) m = fmaxf(m, __shfl_xor(m, off));
    float p = 0.f;
    if (lane < 10)
        p = __expf(val[0] - m) + __expf(val[1] - m) + __expf(val[2] - m) + __expf(val[3] - m);
    #pragma unroll
    for (int off = 1; off < 16; off <<= 1) p += __shfl_xor(p, off);
    float lse = m + __logf(p);
    if (lane < 10) {
        float4 o;
        o.x = val[0] - lse; o.y = val[1] - lse; o.z = val[2] - lse; o.w = val[3] - lse;
        *(float4*)&out[(size_t)node * F_OUT + (c << 2)] = o;
    }
}

extern "C" void kernel_launch(void* const* d_in, const int* in_sizes, int n_in,
                              void* d_out, int out_size, void* d_ws, size_t ws_size,
                              hipStream_t stream) {
    const float* x  = (const float*)d_in[0];
    const int*   ei = (const int*)d_in[1];
    const float* W1 = (const float*)d_in[2];
    const float* b1 = (const float*)d_in[3];
    const float* W2 = (const float*)d_in[4];
    const float* b2 = (const float*)d_in[5];
    const int* src = ei;
    const int* dst = ei + N_EDGES;

    // workspace layout (all chunks 16B-aligned)
    char* p = (char*)d_ws;
    int*    bcursor  = (int*)p;     p += (size_t)(NBINS + 8) * 4;
    int*    bins     = (int*)p;     p += (size_t)NBINS * BIN_CAP * 4;
    int*    csr_src  = (int*)p;     p += (size_t)NBINS * BIN_CAP * 4;
    int*    rowstart = (int*)p;     p += (size_t)(N_NODES + 4) * 4;
    int*    rowcnt   = (int*)p;     p += (size_t)(N_NODES + 4) * 4;
    float*  dinv     = (float*)p;   p += (size_t)N_NODES * 4;
    uint*   Wtb      = (uint*)p;    p += (size_t)4096 * 4;       // W1^T bf16 [64][128]
    ushort* h1b      = (ushort*)p;  p += (size_t)N_NODES * F_HID * 2;
    ushort* h2b      = (ushort*)p;  p += (size_t)N_NODES * F_OUT * 2;
    float*  out      = (float*)d_out;

    prep_kernel   <<<1, 512, 0, stream>>>(W1, Wtb, bcursor);
    binfill_kernel<<<FILL_BLOCKS, 256, 0, stream>>>(src, dst, bcursor, bins, N_EDGES);
    binsort_kernel<<<NBINS, 512, 0, stream>>>(bcursor, bins, csr_src, rowstart, rowcnt, dinv);
    gemm1_kernel  <<<(N_NODES + 63) / 64, 256, 0, stream>>>(x, Wtb, h1b, N_NODES);
    agg1_kernel   <<<N_NODES / 4, 256, 0, stream>>>(rowstart, rowcnt, csr_src, dinv,
                                                    h1b, b1, W2, h2b, N_NODES);
    agg2_kernel   <<<(N_NODES + 3) / 4, 256, 0, stream>>>(rowstart, rowcnt, csr_src, dinv,
                                                          h2b, b2, out, N_NODES);
}

// Round 14
// 286.123 us; speedup vs baseline: 1.0145x; 1.0145x over previous
//
#include <hip/hip_runtime.h>
#include <math.h>

#define N_NODES 100000
#define N_EDGES 1600000
#define F_IN    128
#define F_HID   64
#define F_OUT   40

#define BIN_SHIFT 8
#define NBINS     392          // ceil(100000 / 256)
#define BIN_CAP   5120         // mean ~4082 -> generous headroom
#define FILL_BLOCKS 512

typedef unsigned int  uint;
typedef unsigned short ushort;
typedef __attribute__((ext_vector_type(8))) short bf16x8;   // 4 VGPRs
typedef __attribute__((ext_vector_type(4))) float f32x4;    // MFMA acc

__device__ __forceinline__ unsigned short f2bf(float f) {      // RNE, finite inputs
    uint u = __float_as_uint(f);
    u = (u + 0x7FFF + ((u >> 16) & 1)) >> 16;
    return (unsigned short)u;
}
__device__ __forceinline__ uint pack2bf(float a, float b) {
    return (uint)f2bf(a) | ((uint)f2bf(b) << 16);
}
__device__ __forceinline__ float bf_lo(uint u) { return __uint_as_float(u << 16); }
__device__ __forceinline__ float bf_hi(uint u) { return __uint_as_float(u & 0xFFFF0000u); }

// ---------------- prep: bin cursor init + W1 transpose to bf16 Wt[n(64)][k(128)] --
__global__ void prep_kernel(const float* __restrict__ W, uint* __restrict__ Wt,
                            int* __restrict__ bcursor) {
    int tid = threadIdx.x;                        // 512 threads
    if (tid < NBINS) bcursor[tid] = tid * BIN_CAP;
    for (int i = tid; i < 4096; i += 512) {       // uint index: c*64 + kpair
        int c  = i >> 6;
        int kp = i & 63;
        Wt[i] = pack2bf(W[(2 * kp) * F_HID + c], W[(2 * kp + 1) * F_HID + c]);
    }
}

// ---------------- binned scatter of packed (src | ldst<<17) into padded bins ------
__global__ void binfill_kernel(const int* __restrict__ src, const int* __restrict__ dst,
                               int* __restrict__ bcursor, int* __restrict__ bins, int E) {
    __shared__ int lcount[NBINS];
    __shared__ int gbase[NBINS];
    int tid = threadIdx.x;
    for (int i = tid; i < NBINS; i += 256) lcount[i] = 0;
    __syncthreads();
    int chunk = (E + gridDim.x - 1) / gridDim.x;
    int beg = blockIdx.x * chunk, end = min(E, beg + chunk);
    for (int e = beg + tid; e < end; e += 256)
        atomicAdd(&lcount[dst[e] >> BIN_SHIFT], 1);
    __syncthreads();
    for (int i = tid; i < NBINS; i += 256) {
        gbase[i] = lcount[i] ? atomicAdd(&bcursor[i], lcount[i]) : 0;
        lcount[i] = 0;
    }
    __syncthreads();
    for (int e = beg + tid; e < end; e += 256) {
        int d = dst[e];
        int b = d >> BIN_SHIFT;
        int p = atomicAdd(&lcount[b], 1);
        bins[gbase[b] + p] = src[e] | ((d & 255) << 17);
    }
}

// ---------------- per-bin counting sort; emits rowstart/rowcnt/dinv/csr -----------
__global__ void binsort_kernel(const int* __restrict__ bcursor, const int* __restrict__ bins,
                               int* __restrict__ csr, int* __restrict__ rowstart,
                               int* __restrict__ rowcnt, float* __restrict__ dinv) {
    __shared__ int hist[256];
    __shared__ int scan[256];
    __shared__ int cur[256];
    __shared__ int sorted[BIN_CAP];
    int b = blockIdx.x, t = threadIdx.x;          // 512 threads
    int base = b * BIN_CAP;
    int cnt = bcursor[b] - base;
    if (t < 256) hist[t] = 0;
    __syncthreads();
    for (int i = t; i < cnt; i += 512)
        atomicAdd(&hist[(unsigned)bins[base + i] >> 17], 1);
    __syncthreads();
    int v = 0;
    if (t < 256) { v = hist[t]; scan[t] = v; }
    __syncthreads();
    for (int off = 1; off < 256; off <<= 1) {
        int u = (t < 256 && t >= off) ? scan[t - off] : 0;
        __syncthreads();
        if (t < 256) scan[t] += u;
        __syncthreads();
    }
    if (t < 256) {
        int excl = scan[t] - v;
        cur[t] = excl;
        int node = (b << BIN_SHIFT) + t;
        if (node < N_NODES) {
            rowstart[node] = base + excl;
            rowcnt[node]   = v;
            dinv[node] = rsqrtf((float)v + 1.0f);   // +1 self-loop
        }
    }
    __syncthreads();
    for (int i = t; i < cnt; i += 512) {
        int p   = bins[base + i];
        int pos = atomicAdd(&cur[(unsigned)p >> 17], 1);
        sorted[pos] = p & 0x1FFFF;
    }
    __syncthreads();
    for (int i = t; i < cnt; i += 512)
        csr[base + i] = sorted[i];
}

// ---------------- GEMM1 (MFMA): h1b[N,64](bf16) = bf16(x) @ bf16(W1) ----------------
#define XPITCH 68   // uints per row (64 + 4 pad)
__global__ __launch_bounds__(256) void gemm1_kernel(const float* __restrict__ x,
                                                    const uint* __restrict__ Wt,
                                                    ushort* __restrict__ h, int n) {
    __shared__ __align__(16) uint Xu[64 * XPITCH];
    __shared__ __align__(16) uint Wu[64 * XPITCH];
    int tid = threadIdx.x;
    int node0 = blockIdx.x * 64;

    {
        int c = tid >> 2, qq = tid & 3;
        const uint4* gsrc = (const uint4*)&Wt[c * 64 + qq * 16];
        uint4* ldst = (uint4*)&Wu[c * XPITCH + qq * 16];
        #pragma unroll
        for (int j = 0; j < 4; ++j) ldst[j] = gsrc[j];
    }
    {
        int row = tid >> 2, qq = tid & 3;
        int node = node0 + row;
        uint4* ldst = (uint4*)&Xu[row * XPITCH + qq * 16];
        if (node < n) {
            const float4* gsrc = (const float4*)&x[(size_t)node * F_IN + qq * 32];
            #pragma unroll
            for (int j = 0; j < 4; ++j) {
                float4 a = gsrc[2 * j], b = gsrc[2 * j + 1];
                uint4 o;
                o.x = pack2bf(a.x, a.y); o.y = pack2bf(a.z, a.w);
                o.z = pack2bf(b.x, b.y); o.w = pack2bf(b.z, b.w);
                ldst[j] = o;
            }
        } else {
            uint4 z = make_uint4(0, 0, 0, 0);
            #pragma unroll
            for (int j = 0; j < 4; ++j) ldst[j] = z;
        }
    }
    __syncthreads();

    int wv   = tid >> 6;
    int lane = tid & 63;
    int lrow = lane & 15;
    int quad = lane >> 4;

    bf16x8 bfrag[4][4];
    #pragma unroll
    for (int t = 0; t < 4; ++t)
        #pragma unroll
        for (int s = 0; s < 4; ++s)
            bfrag[t][s] = *(const bf16x8*)&Wu[(t * 16 + lrow) * XPITCH + s * 16 + quad * 4];

    f32x4 acc[4];
    #pragma unroll
    for (int t = 0; t < 4; ++t) acc[t] = (f32x4){0.f, 0.f, 0.f, 0.f};

    #pragma unroll
    for (int s = 0; s < 4; ++s) {
        bf16x8 afrag = *(const bf16x8*)&Xu[(wv * 16 + lrow) * XPITCH + s * 16 + quad * 4];
        #pragma unroll
        for (int t = 0; t < 4; ++t)
            acc[t] = __builtin_amdgcn_mfma_f32_16x16x32_bf16(afrag, bfrag[t][s], acc[t], 0, 0, 0);
    }

    #pragma unroll
    for (int t = 0; t < 4; ++t) {
        #pragma unroll
        for (int i = 0; i < 4; ++i) {
            int node = node0 + wv * 16 + quad * 4 + i;
            if (node < n) h[(size_t)node * F_HID + t * 16 + lrow] = f2bf(acc[t][i]);
        }
    }
}

// ---------------- layer-1 gather + combine + ReLU (1 node/wave, x2 unroll) --------
__global__ void agg1_kernel(const int* __restrict__ rowstart, const int* __restrict__ rowcnt,
                            const int* __restrict__ csr, const float* __restrict__ dinv,
                            const ushort* __restrict__ h, const float* __restrict__ b,
                            ushort* __restrict__ out, int n) {
    int node = blockIdx.x * 4 + (threadIdx.x >> 6);
    int lane = threadIdx.x & 63;
    if (node >= n) return;
    int slot = lane >> 3;        // 0..7
    int c    = lane & 7;         // chunk -> features c*8 .. c*8+7
    int beg = rowstart[node], end = beg + rowcnt[node];
    float acc[8] = {0.f,0.f,0.f,0.f,0.f,0.f,0.f,0.f};
    for (int base = beg; base < end; base += 64) {
        int idx = base + lane;
        int   sid = 0; float wgt = 0.f;
        if (idx < end) { sid = csr[idx]; wgt = dinv[sid]; }
        int cnt    = min(64, end - base);
        int groups = (cnt + 7) >> 3;
        int g = 0;
        for (; g + 2 <= groups; g += 2) {
            int   sA = __shfl(sid, g * 8 + slot);
            float wA = __shfl(wgt, g * 8 + slot);
            int   sB = __shfl(sid, g * 8 + 8 + slot);
            float wB = __shfl(wgt, g * 8 + 8 + slot);
            uint4 hA = *(const uint4*)&h[(size_t)sA * F_HID + (c << 3)];
            uint4 hB = *(const uint4*)&h[(size_t)sB * F_HID + (c << 3)];
            acc[0] += bf_lo(hA.x) * wA; acc[1] += bf_hi(hA.x) * wA;
            acc[2] += bf_lo(hA.y) * wA; acc[3] += bf_hi(hA.y) * wA;
            acc[4] += bf_lo(hA.z) * wA; acc[5] += bf_hi(hA.z) * wA;
            acc[6] += bf_lo(hA.w) * wA; acc[7] += bf_hi(hA.w) * wA;
            acc[0] += bf_lo(hB.x) * wB; acc[1] += bf_hi(hB.x) * wB;
            acc[2] += bf_lo(hB.y) * wB; acc[3] += bf_hi(hB.y) * wB;
            acc[4] += bf_lo(hB.z) * wB; acc[5] += bf_hi(hB.z) * wB;
            acc[6] += bf_lo(hB.w) * wB; acc[7] += bf_hi(hB.w) * wB;
        }
        if (g < groups) {
            int   sA = __shfl(sid, g * 8 + slot);
            float wA = __shfl(wgt, g * 8 + slot);
            uint4 hA = *(const uint4*)&h[(size_t)sA * F_HID + (c << 3)];
            acc[0] += bf_lo(hA.x) * wA; acc[1] += bf_hi(hA.x) * wA;
            acc[2] += bf_lo(hA.y) * wA; acc[3] += bf_hi(hA.y) * wA;
            acc[4] += bf_lo(hA.z) * wA; acc[5] += bf_hi(hA.z) * wA;
            acc[6] += bf_lo(hA.w) * wA; acc[7] += bf_hi(hA.w) * wA;
        }
    }
    #pragma unroll
    for (int m = 8; m < 64; m <<= 1) {
        #pragma unroll
        for (int k = 0; k < 8; ++k) acc[k] += __shfl_xor(acc[k], m);
    }
    if (slot == 0) {
        float di = dinv[node];
        uint4 hs = *(const uint4*)&h[(size_t)node * F_HID + (c << 3)];
        float self[8] = { bf_lo(hs.x), bf_hi(hs.x), bf_lo(hs.y), bf_hi(hs.y),
                          bf_lo(hs.z), bf_hi(hs.z), bf_lo(hs.w), bf_hi(hs.w) };
        float4 b0 = *(const float4*)&b[c << 3];
        float4 b1v = *(const float4*)&b[(c << 3) + 4];
        float bb[8] = { b0.x, b0.y, b0.z, b0.w, b1v.x, b1v.y, b1v.z, b1v.w };
        ushort o[8];
        #pragma unroll
        for (int k = 0; k < 8; ++k) {
            float v = fmaxf(acc[k] * di + self[k] * di * di + bb[k], 0.f);
            o[k] = f2bf(v);
        }
        uint4 pk;
        pk.x = (uint)o[0] | ((uint)o[1] << 16);
        pk.y = (uint)o[2] | ((uint)o[3] << 16);
        pk.z = (uint)o[4] | ((uint)o[5] << 16);
        pk.w = (uint)o[6] | ((uint)o[7] << 16);
        *(uint4*)&out[(size_t)node * F_HID + (c << 3)] = pk;
    }
}

// ---------------- GEMM2: h2b[N,40](bf16) = out1b[N,64](bf16) @ W2[64,40] ----------
__global__ void gemm2_kernel(const ushort* __restrict__ a, const float* __restrict__ W,
                             ushort* __restrict__ h, int n) {
    __shared__ float Wl[F_HID * F_OUT];
    int tid = threadIdx.x;
    for (int i = tid; i < F_HID * F_OUT; i += 256) Wl[i] = W[i];
    __syncthreads();
    long long idx = (long long)blockIdx.x * 256 + tid;
    if (idx >= (long long)n * F_OUT) return;
    int node = (int)(idx / F_OUT);
    int col  = (int)(idx - (long long)node * F_OUT);
    const uint* arow = (const uint*)(a + (size_t)node * F_HID);
    float acc = 0.0f;
    #pragma unroll 8
    for (int k = 0; k < F_HID / 2; ++k) {
        uint u = arow[k];
        acc += bf_lo(u) * Wl[(2 * k) * F_OUT + col] + bf_hi(u) * Wl[(2 * k + 1) * F_OUT + col];
    }
    h[idx] = f2bf(acc);
}

// ---------------- layer-2 gather + combine + log_softmax (1 node/wave, uint2) -----
__global__ void agg2_kernel(const int* __restrict__ rowstart, const int* __restrict__ rowcnt,
                            const int* __restrict__ csr, const float* __restrict__ dinv,
                            const ushort* __restrict__ h, const float* __restrict__ b,
                            float* __restrict__ out, int n) {
    int node = blockIdx.x * 4 + (threadIdx.x >> 6);
    int lane = threadIdx.x & 63;
    if (node >= n) return;
    int slot = lane / 10;            // 0..6 (lanes 60..63 idle slot)
    int c    = lane - slot * 10;     // chunk -> features c*4..c*4+3
    int beg = rowstart[node], end = beg + rowcnt[node];
    float acc[4] = {0.f, 0.f, 0.f, 0.f};
    for (int base = beg; base < end; base += 60) {
        int idx = base + lane;
        int   sid = 0; float wgt = 0.f;
        if (lane < 60 && idx < end) { sid = csr[idx]; wgt = dinv[sid]; }
        int cnt    = min(60, end - base);
        int groups = (cnt + 5) / 6;
        int g = 0;
        for (; g + 2 <= groups; g += 2) {
            int   slA = (slot < 6) ? (g * 6 + slot) : 60;
            int   slB = (slot < 6) ? (g * 6 + 6 + slot) : 60;
            int   sA = __shfl(sid, slA);
            float wA = __shfl(wgt, slA);
            int   sB = __shfl(sid, slB);
            float wB = __shfl(wgt, slB);
            uint2 hA = *(const uint2*)&h[(size_t)sA * F_OUT + (c << 2)];
            uint2 hB = *(const uint2*)&h[(size_t)sB * F_OUT + (c << 2)];
            acc[0] += bf_lo(hA.x) * wA; acc[1] += bf_hi(hA.x) * wA;
            acc[2] += bf_lo(hA.y) * wA; acc[3] += bf_hi(hA.y) * wA;
            acc[0] += bf_lo(hB.x) * wB; acc[1] += bf_hi(hB.x) * wB;
            acc[2] += bf_lo(hB.y) * wB; acc[3] += bf_hi(hB.y) * wB;
        }
        if (g < groups) {
            int   slA = (slot < 6) ? (g * 6 + slot) : 60;
            int   sA = __shfl(sid, slA);
            float wA = __shfl(wgt, slA);
            uint2 hA = *(const uint2*)&h[(size_t)sA * F_OUT + (c << 2)];
            acc[0] += bf_lo(hA.x) * wA; acc[1] += bf_hi(hA.x) * wA;
            acc[2] += bf_lo(hA.y) * wA; acc[3] += bf_hi(hA.y) * wA;
        }
    }
    // slot reduction: 6 -> 3 -> 1 (3 serial shfl steps)
    float r[4];
    #pragma unroll
    for (int k = 0; k < 4; ++k) {
        float t3 = __shfl(acc[k], lane + 30);          // slots 3..5 -> 0..2
        float s0 = acc[k] + t3;                        // valid for lanes < 30
        float t1 = __shfl(s0, lane + 10);              // slot 1 -> 0
        float t2 = __shfl(s0, lane + 20);              // slot 2 -> 0
        r[k] = s0 + t1 + t2;                           // valid for lanes < 10
    }
    float val[4] = {0.f, 0.f, 0.f, 0.f};
    float m = -INFINITY;
    if (lane < 10) {
        float di = dinv[node];
        uint2 hs = *(const uint2*)&h[(size_t)node * F_OUT + (c << 2)];
        float self[4] = { bf_lo(hs.x), bf_hi(hs.x), bf_lo(hs.y), bf_hi(hs.y) };
        float4 bb = *(const float4*)&b[c << 2];
        float bbv[4] = { bb.x, bb.y, bb.z, bb.w };
        #pragma unroll
        for (int k = 0; k < 4; ++k) {
            val[k] = r[k] * di + self[k] * di * di + bbv[k];
            m = fmaxf(m, val[k]);
        }
    }
    #pragma unroll
    for (int off = 1; off < 16; off <<= 1) m = fmaxf(m, __shfl_xor(m, off));
    float p = 0.f;
    if (lane < 10)
        p = __expf(val[0] - m) + __expf(val[1] - m) + __expf(val[2] - m) + __expf(val[3] - m);
    #pragma unroll
    for (int off = 1; off < 16; off <<= 1) p += __shfl_xor(p, off);
    float lse = m + __logf(p);
    if (lane < 10) {
        float4 o;
        o.x = val[0] - lse; o.y = val[1] - lse; o.z = val[2] - lse; o.w = val[3] - lse;
        *(float4*)&out[(size_t)node * F_OUT + (c << 2)] = o;
    }
}

extern "C" void kernel_launch(void* const* d_in, const int* in_sizes, int n_in,
                              void* d_out, int out_size, void* d_ws, size_t ws_size,
                              hipStream_t stream) {
    const float* x  = (const float*)d_in[0];
    const int*   ei = (const int*)d_in[1];
    const float* W1 = (const float*)d_in[2];
    const float* b1 = (const float*)d_in[3];
    const float* W2 = (const float*)d_in[4];
    const float* b2 = (const float*)d_in[5];
    const int* src = ei;
    const int* dst = ei + N_EDGES;

    // workspace layout (all chunks 16B-aligned)
    char* p = (char*)d_ws;
    int*    bcursor  = (int*)p;     p += (size_t)(NBINS + 8) * 4;
    int*    bins     = (int*)p;     p += (size_t)NBINS * BIN_CAP * 4;
    int*    csr_src  = (int*)p;     p += (size_t)NBINS * BIN_CAP * 4;
    int*    rowstart = (int*)p;     p += (size_t)(N_NODES + 4) * 4;
    int*    rowcnt   = (int*)p;     p += (size_t)(N_NODES + 4) * 4;
    float*  dinv     = (float*)p;   p += (size_t)N_NODES * 4;
    uint*   Wtb      = (uint*)p;    p += (size_t)4096 * 4;       // W1^T bf16 [64][128]
    ushort* h1b      = (ushort*)p;  p += (size_t)N_NODES * F_HID * 2;
    ushort* out1b    = (ushort*)p;  p += (size_t)N_NODES * F_HID * 2;
    ushort* h2b      = (ushort*)p;  p += (size_t)N_NODES * F_OUT * 2;
    float*  out      = (float*)d_out;

    prep_kernel   <<<1, 512, 0, stream>>>(W1, Wtb, bcursor);
    binfill_kernel<<<FILL_BLOCKS, 256, 0, stream>>>(src, dst, bcursor, bins, N_EDGES);
    binsort_kernel<<<NBINS, 512, 0, stream>>>(bcursor, bins, csr_src, rowstart, rowcnt, dinv);
    gemm1_kernel  <<<(N_NODES + 63) / 64, 256, 0, stream>>>(x, Wtb, h1b, N_NODES);
    agg1_kernel   <<<(N_NODES + 3) / 4, 256, 0, stream>>>(rowstart, rowcnt, csr_src, dinv,
                                                          h1b, b1, out1b, N_NODES);
    gemm2_kernel  <<<((N_NODES * F_OUT) + 255) / 256, 256, 0, stream>>>(out1b, W2, h2b, N_NODES);
    agg2_kernel   <<<(N_NODES + 3) / 4, 256, 0, stream>>>(rowstart, rowcnt, csr_src, dinv,
                                                          h2b, b2, out, N_NODES);
}

// Round 15
// 282.003 us; speedup vs baseline: 1.0293x; 1.0146x over previous
//
#include <hip/hip_runtime.h>
#include <math.h>

#define N_NODES 100000
#define N_EDGES 1600000
#define F_IN    128
#define F_HID   64
#define F_OUT   40

#define BIN_SHIFT 8
#define NBINS     392          // ceil(100000 / 256)
#define BIN_CAP   5120         // mean ~4082 -> generous headroom
#define FILL_BLOCKS 512
#define GEMM1_BLOCKS ((N_NODES + 63) / 64)

typedef unsigned int  uint;
typedef unsigned short ushort;
typedef __attribute__((ext_vector_type(8))) short bf16x8;   // 4 VGPRs
typedef __attribute__((ext_vector_type(4))) float f32x4;    // MFMA acc

__device__ __forceinline__ unsigned short f2bf(float f) {      // RNE, finite inputs
    uint u = __float_as_uint(f);
    u = (u + 0x7FFF + ((u >> 16) & 1)) >> 16;
    return (unsigned short)u;
}
__device__ __forceinline__ uint pack2bf(float a, float b) {
    return (uint)f2bf(a) | ((uint)f2bf(b) << 16);
}
__device__ __forceinline__ float bf_lo(uint u) { return __uint_as_float(u << 16); }
__device__ __forceinline__ float bf_hi(uint u) { return __uint_as_float(u & 0xFFFF0000u); }

// ---------------- prep: bin cursor init + W1 transpose to bf16 Wt[n(64)][k(128)] --
__global__ void prep_kernel(const float* __restrict__ W, uint* __restrict__ Wt,
                            int* __restrict__ bcursor) {
    int tid = threadIdx.x;                        // 512 threads
    if (tid < NBINS) bcursor[tid] = tid * BIN_CAP;
    for (int i = tid; i < 4096; i += 512) {       // uint index: c*64 + kpair
        int c  = i >> 6;
        int kp = i & 63;
        Wt[i] = pack2bf(W[(2 * kp) * F_HID + c], W[(2 * kp + 1) * F_HID + c]);
    }
}

// ---------------- fused: binned edge scatter (blocks 0..511) | GEMM1 (rest) -------
// binfill: scatter packed (src | ldst<<17) into padded bins.
// gemm1 (MFMA): h1b[N,64](bf16) = bf16(x) @ bf16(W1); independent of binfill.
#define XPITCH 68   // uints per row (64 + 4 pad)
__global__ __launch_bounds__(256) void fillgemm_kernel(
        const int* __restrict__ src, const int* __restrict__ dst,
        int* __restrict__ bcursor, int* __restrict__ bins, int E,
        const float* __restrict__ x, const uint* __restrict__ Wt,
        ushort* __restrict__ h, int n) {
    __shared__ __align__(16) uint smem[2 * 64 * XPITCH];   // 34.8 KB union
    int tid = threadIdx.x;

    if (blockIdx.x < FILL_BLOCKS) {
        // ---------------- binfill path ----------------
        int* lcount = (int*)smem;
        int* gbase  = ((int*)smem) + NBINS;
        for (int i = tid; i < NBINS; i += 256) lcount[i] = 0;
        __syncthreads();
        int chunk = (E + FILL_BLOCKS - 1) / FILL_BLOCKS;
        int beg = blockIdx.x * chunk, end = min(E, beg + chunk);
        for (int e = beg + tid; e < end; e += 256)
            atomicAdd(&lcount[dst[e] >> BIN_SHIFT], 1);
        __syncthreads();
        for (int i = tid; i < NBINS; i += 256) {
            gbase[i] = lcount[i] ? atomicAdd(&bcursor[i], lcount[i]) : 0;
            lcount[i] = 0;
        }
        __syncthreads();
        for (int e = beg + tid; e < end; e += 256) {
            int d = dst[e];
            int b = d >> BIN_SHIFT;
            int p = atomicAdd(&lcount[b], 1);
            bins[gbase[b] + p] = src[e] | ((d & 255) << 17);
        }
        return;
    }

    // ---------------- gemm1 path ----------------
    uint* Xu = smem;
    uint* Wu = smem + 64 * XPITCH;
    int node0 = (blockIdx.x - FILL_BLOCKS) * 64;

    {
        int c = tid >> 2, qq = tid & 3;
        const uint4* gsrc = (const uint4*)&Wt[c * 64 + qq * 16];
        uint4* ldst = (uint4*)&Wu[c * XPITCH + qq * 16];
        #pragma unroll
        for (int j = 0; j < 4; ++j) ldst[j] = gsrc[j];
    }
    {
        int row = tid >> 2, qq = tid & 3;
        int node = node0 + row;
        uint4* ldst = (uint4*)&Xu[row * XPITCH + qq * 16];
        if (node < n) {
            const float4* gsrc = (const float4*)&x[(size_t)node * F_IN + qq * 32];
            #pragma unroll
            for (int j = 0; j < 4; ++j) {
                float4 a = gsrc[2 * j], b = gsrc[2 * j + 1];
                uint4 o;
                o.x = pack2bf(a.x, a.y); o.y = pack2bf(a.z, a.w);
                o.z = pack2bf(b.x, b.y); o.w = pack2bf(b.z, b.w);
                ldst[j] = o;
            }
        } else {
            uint4 z = make_uint4(0, 0, 0, 0);
            #pragma unroll
            for (int j = 0; j < 4; ++j) ldst[j] = z;
        }
    }
    __syncthreads();

    int wv   = tid >> 6;
    int lane = tid & 63;
    int lrow = lane & 15;
    int quad = lane >> 4;

    bf16x8 bfrag[4][4];
    #pragma unroll
    for (int t = 0; t < 4; ++t)
        #pragma unroll
        for (int s = 0; s < 4; ++s)
            bfrag[t][s] = *(const bf16x8*)&Wu[(t * 16 + lrow) * XPITCH + s * 16 + quad * 4];

    f32x4 acc[4];
    #pragma unroll
    for (int t = 0; t < 4; ++t) acc[t] = (f32x4){0.f, 0.f, 0.f, 0.f};

    #pragma unroll
    for (int s = 0; s < 4; ++s) {
        bf16x8 afrag = *(const bf16x8*)&Xu[(wv * 16 + lrow) * XPITCH + s * 16 + quad * 4];
        #pragma unroll
        for (int t = 0; t < 4; ++t)
            acc[t] = __builtin_amdgcn_mfma_f32_16x16x32_bf16(afrag, bfrag[t][s], acc[t], 0, 0, 0);
    }

    #pragma unroll
    for (int t = 0; t < 4; ++t) {
        #pragma unroll
        for (int i = 0; i < 4; ++i) {
            int node = node0 + wv * 16 + quad * 4 + i;
            if (node < n) h[(size_t)node * F_HID + t * 16 + lrow] = f2bf(acc[t][i]);
        }
    }
}

// ---------------- per-bin counting sort; emits rowstart/rowcnt/dinv/csr -----------
__global__ void binsort_kernel(const int* __restrict__ bcursor, const int* __restrict__ bins,
                               int* __restrict__ csr, int* __restrict__ rowstart,
                               int* __restrict__ rowcnt, float* __restrict__ dinv) {
    __shared__ int hist[256];
    __shared__ int scan[256];
    __shared__ int cur[256];
    __shared__ int sorted[BIN_CAP];
    int b = blockIdx.x, t = threadIdx.x;          // 512 threads
    int base = b * BIN_CAP;
    int cnt = bcursor[b] - base;
    if (t < 256) hist[t] = 0;
    __syncthreads();
    for (int i = t; i < cnt; i += 512)
        atomicAdd(&hist[(unsigned)bins[base + i] >> 17], 1);
    __syncthreads();
    int v = 0;
    if (t < 256) { v = hist[t]; scan[t] = v; }
    __syncthreads();
    for (int off = 1; off < 256; off <<= 1) {
        int u = (t < 256 && t >= off) ? scan[t - off] : 0;
        __syncthreads();
        if (t < 256) scan[t] += u;
        __syncthreads();
    }
    if (t < 256) {
        int excl = scan[t] - v;
        cur[t] = excl;
        int node = (b << BIN_SHIFT) + t;
        if (node < N_NODES) {
            rowstart[node] = base + excl;
            rowcnt[node]   = v;
            dinv[node] = rsqrtf((float)v + 1.0f);   // +1 self-loop
        }
    }
    __syncthreads();
    for (int i = t; i < cnt; i += 512) {
        int p   = bins[base + i];
        int pos = atomicAdd(&cur[(unsigned)p >> 17], 1);
        sorted[pos] = p & 0x1FFFF;
    }
    __syncthreads();
    for (int i = t; i < cnt; i += 512)
        csr[base + i] = sorted[i];
}

// ---------------- layer-1 gather + combine + ReLU (1 node/wave, x2 unroll) --------
__global__ void agg1_kernel(const int* __restrict__ rowstart, const int* __restrict__ rowcnt,
                            const int* __restrict__ csr, const float* __restrict__ dinv,
                            const ushort* __restrict__ h, const float* __restrict__ b,
                            ushort* __restrict__ out, int n) {
    int node = blockIdx.x * 4 + (threadIdx.x >> 6);
    int lane = threadIdx.x & 63;
    if (node >= n) return;
    int slot = lane >> 3;        // 0..7
    int c    = lane & 7;         // chunk -> features c*8 .. c*8+7
    int beg = rowstart[node], end = beg + rowcnt[node];
    float acc[8] = {0.f,0.f,0.f,0.f,0.f,0.f,0.f,0.f};
    for (int base = beg; base < end; base += 64) {
        int idx = base + lane;
        int   sid = 0; float wgt = 0.f;
        if (idx < end) { sid = csr[idx]; wgt = dinv[sid]; }
        int cnt    = min(64, end - base);
        int groups = (cnt + 7) >> 3;
        int g = 0;
        for (; g + 2 <= groups; g += 2) {
            int   sA = __shfl(sid, g * 8 + slot);
            float wA = __shfl(wgt, g * 8 + slot);
            int   sB = __shfl(sid, g * 8 + 8 + slot);
            float wB = __shfl(wgt, g * 8 + 8 + slot);
            uint4 hA = *(const uint4*)&h[(size_t)sA * F_HID + (c << 3)];
            uint4 hB = *(const uint4*)&h[(size_t)sB * F_HID + (c << 3)];
            acc[0] += bf_lo(hA.x) * wA; acc[1] += bf_hi(hA.x) * wA;
            acc[2] += bf_lo(hA.y) * wA; acc[3] += bf_hi(hA.y) * wA;
            acc[4] += bf_lo(hA.z) * wA; acc[5] += bf_hi(hA.z) * wA;
            acc[6] += bf_lo(hA.w) * wA; acc[7] += bf_hi(hA.w) * wA;
            acc[0] += bf_lo(hB.x) * wB; acc[1] += bf_hi(hB.x) * wB;
            acc[2] += bf_lo(hB.y) * wB; acc[3] += bf_hi(hB.y) * wB;
            acc[4] += bf_lo(hB.z) * wB; acc[5] += bf_hi(hB.z) * wB;
            acc[6] += bf_lo(hB.w) * wB; acc[7] += bf_hi(hB.w) * wB;
        }
        if (g < groups) {
            int   sA = __shfl(sid, g * 8 + slot);
            float wA = __shfl(wgt, g * 8 + slot);
            uint4 hA = *(const uint4*)&h[(size_t)sA * F_HID + (c << 3)];
            acc[0] += bf_lo(hA.x) * wA; acc[1] += bf_hi(hA.x) * wA;
            acc[2] += bf_lo(hA.y) * wA; acc[3] += bf_hi(hA.y) * wA;
            acc[4] += bf_lo(hA.z) * wA; acc[5] += bf_hi(hA.z) * wA;
            acc[6] += bf_lo(hA.w) * wA; acc[7] += bf_hi(hA.w) * wA;
        }
    }
    #pragma unroll
    for (int m = 8; m < 64; m <<= 1) {
        #pragma unroll
        for (int k = 0; k < 8; ++k) acc[k] += __shfl_xor(acc[k], m);
    }
    if (slot == 0) {
        float di = dinv[node];
        uint4 hs = *(const uint4*)&h[(size_t)node * F_HID + (c << 3)];
        float self[8] = { bf_lo(hs.x), bf_hi(hs.x), bf_lo(hs.y), bf_hi(hs.y),
                          bf_lo(hs.z), bf_hi(hs.z), bf_lo(hs.w), bf_hi(hs.w) };
        float4 b0 = *(const float4*)&b[c << 3];
        float4 b1v = *(const float4*)&b[(c << 3) + 4];
        float bb[8] = { b0.x, b0.y, b0.z, b0.w, b1v.x, b1v.y, b1v.z, b1v.w };
        ushort o[8];
        #pragma unroll
        for (int k = 0; k < 8; ++k) {
            float v = fmaxf(acc[k] * di + self[k] * di * di + bb[k], 0.f);
            o[k] = f2bf(v);
        }
        uint4 pk;
        pk.x = (uint)o[0] | ((uint)o[1] << 16);
        pk.y = (uint)o[2] | ((uint)o[3] << 16);
        pk.z = (uint)o[4] | ((uint)o[5] << 16);
        pk.w = (uint)o[6] | ((uint)o[7] << 16);
        *(uint4*)&out[(size_t)node * F_HID + (c << 3)] = pk;
    }
}

// ---------------- GEMM2: h2b[N,40](bf16) = out1b[N,64](bf16) @ W2[64,40] ----------
__global__ void gemm2_kernel(const ushort* __restrict__ a, const float* __restrict__ W,
                             ushort* __restrict__ h, int n) {
    __shared__ float Wl[F_HID * F_OUT];
    int tid = threadIdx.x;
    for (int i = tid; i < F_HID * F_OUT; i += 256) Wl[i] = W[i];
    __syncthreads();
    long long idx = (long long)blockIdx.x * 256 + tid;
    if (idx >= (long long)n * F_OUT) return;
    int node = (int)(idx / F_OUT);
    int col  = (int)(idx - (long long)node * F_OUT);
    const uint* arow = (const uint*)(a + (size_t)node * F_HID);
    float acc = 0.0f;
    #pragma unroll 8
    for (int k = 0; k < F_HID / 2; ++k) {
        uint u = arow[k];
        acc += bf_lo(u) * Wl[(2 * k) * F_OUT + col] + bf_hi(u) * Wl[(2 * k + 1) * F_OUT + col];
    }
    h[idx] = f2bf(acc);
}

// ---------------- layer-2 gather + combine + log_softmax (1 node/wave, uint2) -----
__global__ void agg2_kernel(const int* __restrict__ rowstart, const int* __restrict__ rowcnt,
                            const int* __restrict__ csr, const float* __restrict__ dinv,
                            const ushort* __restrict__ h, const float* __restrict__ b,
                            float* __restrict__ out, int n) {
    int node = blockIdx.x * 4 + (threadIdx.x >> 6);
    int lane = threadIdx.x & 63;
    if (node >= n) return;
    int slot = lane / 10;            // 0..6 (lanes 60..63 idle slot)
    int c    = lane - slot * 10;     // chunk -> features c*4..c*4+3
    int beg = rowstart[node], end = beg + rowcnt[node];
    float acc[4] = {0.f, 0.f, 0.f, 0.f};
    for (int base = beg; base < end; base += 60) {
        int idx = base + lane;
        int   sid = 0; float wgt = 0.f;
        if (lane < 60 && idx < end) { sid = csr[idx]; wgt = dinv[sid]; }
        int cnt    = min(60, end - base);
        int groups = (cnt + 5) / 6;
        int g = 0;
        for (; g + 2 <= groups; g += 2) {
            int   slA = (slot < 6) ? (g * 6 + slot) : 60;
            int   slB = (slot < 6) ? (g * 6 + 6 + slot) : 60;
            int   sA = __shfl(sid, slA);
            float wA = __shfl(wgt, slA);
            int   sB = __shfl(sid, slB);
            float wB = __shfl(wgt, slB);
            uint2 hA = *(const uint2*)&h[(size_t)sA * F_OUT + (c << 2)];
            uint2 hB = *(const uint2*)&h[(size_t)sB * F_OUT + (c << 2)];
            acc[0] += bf_lo(hA.x) * wA; acc[1] += bf_hi(hA.x) * wA;
            acc[2] += bf_lo(hA.y) * wA; acc[3] += bf_hi(hA.y) * wA;
            acc[0] += bf_lo(hB.x) * wB; acc[1] += bf_hi(hB.x) * wB;
            acc[2] += bf_lo(hB.y) * wB; acc[3] += bf_hi(hB.y) * wB;
        }
        if (g < groups) {
            int   slA = (slot < 6) ? (g * 6 + slot) : 60;
            int   sA = __shfl(sid, slA);
            float wA = __shfl(wgt, slA);
            uint2 hA = *(const uint2*)&h[(size_t)sA * F_OUT + (c << 2)];
            acc[0] += bf_lo(hA.x) * wA; acc[1] += bf_hi(hA.x) * wA;
            acc[2] += bf_lo(hA.y) * wA; acc[3] += bf_hi(hA.y) * wA;
        }
    }
    // slot reduction: 6 -> 3 -> 1 (3 serial shfl steps)
    float r[4];
    #pragma unroll
    for (int k = 0; k < 4; ++k) {
        float t3 = __shfl(acc[k], lane + 30);          // slots 3..5 -> 0..2
        float s0 = acc[k] + t3;                        // valid for lanes < 30
        float t1 = __shfl(s0, lane + 10);              // slot 1 -> 0
        float t2 = __shfl(s0, lane + 20);              // slot 2 -> 0
        r[k] = s0 + t1 + t2;                           // valid for lanes < 10
    }
    float val[4] = {0.f, 0.f, 0.f, 0.f};
    float m = -INFINITY;
    if (lane < 10) {
        float di = dinv[node];
        uint2 hs = *(const uint2*)&h[(size_t)node * F_OUT + (c << 2)];
        float self[4] = { bf_lo(hs.x), bf_hi(hs.x), bf_lo(hs.y), bf_hi(hs.y) };
        float4 bb = *(const float4*)&b[c << 2];
        float bbv[4] = { bb.x, bb.y, bb.z, bb.w };
        #pragma unroll
        for (int k = 0; k < 4; ++k) {
            val[k] = r[k] * di + self[k] * di * di + bbv[k];
            m = fmaxf(m, val[k]);
        }
    }
    #pragma unroll
    for (int off = 1; off < 16; off <<= 1) m = fmaxf(m, __shfl_xor(m, off));
    float p = 0.f;
    if (lane < 10)
        p = __expf(val[0] - m) + __expf(val[1] - m) + __expf(val[2] - m) + __expf(val[3] - m);
    #pragma unroll
    for (int off = 1; off < 16; off <<= 1) p += __shfl_xor(p, off);
    float lse = m + __logf(p);
    if (lane < 10) {
        float4 o;
        o.x = val[0] - lse; o.y = val[1] - lse; o.z = val[2] - lse; o.w = val[3] - lse;
        *(float4*)&out[(size_t)node * F_OUT + (c << 2)] = o;
    }
}

extern "C" void kernel_launch(void* const* d_in, const int* in_sizes, int n_in,
                              void* d_out, int out_size, void* d_ws, size_t ws_size,
                              hipStream_t stream) {
    const float* x  = (const float*)d_in[0];
    const int*   ei = (const int*)d_in[1];
    const float* W1 = (const float*)d_in[2];
    const float* b1 = (const float*)d_in[3];
    const float* W2 = (const float*)d_in[4];
    const float* b2 = (const float*)d_in[5];
    const int* src = ei;
    const int* dst = ei + N_EDGES;

    // workspace layout (all chunks 16B-aligned)
    char* p = (char*)d_ws;
    int*    bcursor  = (int*)p;     p += (size_t)(NBINS + 8) * 4;
    int*    bins     = (int*)p;     p += (size_t)NBINS * BIN_CAP * 4;
    int*    csr_src  = (int*)p;     p += (size_t)NBINS * BIN_CAP * 4;
    int*    rowstart = (int*)p;     p += (size_t)(N_NODES + 4) * 4;
    int*    rowcnt   = (int*)p;     p += (size_t)(N_NODES + 4) * 4;
    float*  dinv     = (float*)p;   p += (size_t)N_NODES * 4;
    uint*   Wtb      = (uint*)p;    p += (size_t)4096 * 4;       // W1^T bf16 [64][128]
    ushort* h1b      = (ushort*)p;  p += (size_t)N_NODES * F_HID * 2;
    ushort* out1b    = (ushort*)p;  p += (size_t)N_NODES * F_HID * 2;
    ushort* h2b      = (ushort*)p;  p += (size_t)N_NODES * F_OUT * 2;
    float*  out      = (float*)d_out;

    prep_kernel    <<<1, 512, 0, stream>>>(W1, Wtb, bcursor);
    fillgemm_kernel<<<FILL_BLOCKS + GEMM1_BLOCKS, 256, 0, stream>>>(
        src, dst, bcursor, bins, N_EDGES, x, Wtb, h1b, N_NODES);
    binsort_kernel <<<NBINS, 512, 0, stream>>>(bcursor, bins, csr_src, rowstart, rowcnt, dinv);
    agg1_kernel    <<<(N_NODES + 3) / 4, 256, 0, stream>>>(rowstart, rowcnt, csr_src, dinv,
                                                           h1b, b1, out1b, N_NODES);
    gemm2_kernel   <<<((N_NODES * F_OUT) + 255) / 256, 256, 0, stream>>>(out1b, W2, h2b, N_NODES);
    agg2_kernel    <<<(N_NODES + 3) / 4, 256, 0, stream>>>(rowstart, rowcnt, csr_src, dinv,
                                                           h2b, b2, out, N_NODES);
}